// Round 20
// baseline (161.352 us; speedup 1.0000x reference)
//
#include <hip/hip_runtime.h>
#include <math.h>

#define Hc 160
#define Wc 160
#define HWc (Hc*Wc)
#define Cc 64
#define COMC 108

typedef __attribute__((ext_vector_type(8))) short short8;
typedef __attribute__((ext_vector_type(4))) float f32x4;
typedef __attribute__((ext_vector_type(2))) float f32x2;

__device__ inline short f2bf(float f) {
    union { float f; unsigned u; } v; v.f = f;
    unsigned r = (v.u + 0x7FFFu + ((v.u >> 16) & 1u)) >> 16;
    return (short)r;
}
__device__ inline float bf2f(short s) {
    union { unsigned u; float f; } v; v.u = ((unsigned)(unsigned short)s) << 16; return v.f;
}
__device__ inline float bflo(unsigned u) {
    union { unsigned u; float f; } v; v.u = u << 16; return v.f;
}
__device__ inline float bfhi(unsigned u) {
    union { unsigned u; float f; } v; v.u = u & 0xFFFF0000u; return v.f;
}
__device__ inline f32x2 bf2x2(unsigned u) {
    union { unsigned u; float f; } lo, hi;
    lo.u = u << 16; hi.u = u & 0xFFFF0000u;
    return (f32x2){lo.f, hi.f};
}
// round-half-up pack of 2 floats -> 1 dword of 2 bf16, via v_perm (3 ops)
__device__ inline unsigned packbf_perm(float lo, float hi) {
    union { float f; unsigned u; } a, c; a.f = lo; c.f = hi;
    return __builtin_amdgcn_perm(c.u + 0x8000u, a.u + 0x8000u, 0x07060302u);
}

// ---- prep: fragment-ordered bf16 weights for all three MFMA stages ----------
__global__ __launch_bounds__(256) void k_prep2(
    const float* __restrict__ w_off,
    const float* __restrict__ bn_g, const float* __restrict__ bn_b,
    const float* __restrict__ bn_m, const float* __restrict__ bn_v,
    const float* __restrict__ w_com, const float* __restrict__ w_dcn,
    short* __restrict__ wof_frag, float* __restrict__ shift,
    short* __restrict__ wfrag, short* __restrict__ wdT)
{
    const int t = blockIdx.x * 256 + threadIdx.x;
    if (t < 64) {
        const float scale = bn_g[t] * __frsqrt_rn(bn_v[t] + 1e-5f);
        shift[t] = bn_b[t] - bn_m[t] * scale;
    }
    if (t < 4096) {  // wof_frag [4m][2s][64 lane][8 j]
        const int j = t & 7;
        const int lane = (t >> 3) & 63;
        const int v = t >> 9;            // m*2+s
        const int s = v & 1, m = v >> 1;
        const int o = m*16 + (lane & 15);
        const int i = s*32 + (lane >> 4)*8 + j;
        const float scale = bn_g[o] * __frsqrt_rn(bn_v[o] + 1e-5f);
        wof_frag[t] = f2bf(w_off[o*64 + i] * scale);
    }
    if (t < 64512) {  // wfrag [7 mtile][18 s][64 lane][8 j]; K-order = kk*64 + i
        const int j = t & 7;
        const int lane = (t >> 3) & 63;
        const int v = t >> 9;            // 0..125
        const int s = v % 18, m = v / 18;
        const int kk = s >> 1, h = s & 1;
        const int o = m*16 + (lane & 15);
        const int i = h*32 + (lane >> 4)*8 + j;
        wfrag[t] = (o < COMC) ? f2bf(w_com[(o*64 + i)*9 + kk]) : (short)0;
    }
    if (t < 36864) {  // wdT [4 mtile][18 s][64 lane][8 j]; K-order = kk*64 + ch
        const int j = t & 7;
        const int lane = (t >> 3) & 63;
        const int v = t >> 9;            // 0..71
        const int s = v % 18, m = v / 18;
        const int o = m*16 + (lane & 15);
        const int q = s*32 + (lane >> 4)*8 + j;  // 0..575
        const int ch = q & 63, kk = q >> 6;
        wdT[t] = f2bf(w_dcn[o*576 + ch*9 + kk]);
    }
}

// ---- Kernel A: off_bf = BN(fea @ w_off^T) via MFMA; emits group-planar fea_gp
__global__ __launch_bounds__(256) void k_off3(
    const float* __restrict__ fea, const short* __restrict__ wof_frag,
    const float* __restrict__ shift,
    short* __restrict__ off_bf, short* __restrict__ fea_gp)
{
    __shared__ short sm[64][72];
    const int b = blockIdx.y;
    const int w = threadIdx.x >> 6, lane = threadIdx.x & 63;
    const int n = lane & 15, g = lane >> 4;
    const int p = blockIdx.x * 64 + w * 16 + n;
    const float* f = fea + (size_t)b * Cc * HWc + p;

    short8 bfrag[2];
    #pragma unroll
    for (int s = 0; s < 2; ++s) {
        #pragma unroll
        for (int j = 0; j < 8; ++j)
            bfrag[s][j] = f2bf(f[(size_t)(s*32 + g*8 + j) * HWc]);
        const int gg = s*2 + (g >> 1);
        *(short8*)&fea_gp[(((size_t)b*4 + gg)*HWc + p)*16 + (g & 1)*8] = bfrag[s];
    }

    f32x4 acc[4];
    #pragma unroll
    for (int m = 0; m < 4; ++m) acc[m] = (f32x4){0.f, 0.f, 0.f, 0.f};
    #pragma unroll
    for (int s = 0; s < 2; ++s) {
        #pragma unroll
        for (int m = 0; m < 4; ++m) {
            const short8 afrag = *(const short8*)&wof_frag[((m*2 + s)*64 + lane)*8];
            acc[m] = __builtin_amdgcn_mfma_f32_16x16x32_bf16(afrag, bfrag[s], acc[m], 0, 0, 0);
        }
    }
    #pragma unroll
    for (int m = 0; m < 4; ++m) {
        #pragma unroll
        for (int r = 0; r < 4; ++r) {
            const int o = m*16 + g*4 + r;
            sm[w*16 + n][o] = f2bf(acc[m][r] + shift[o]);
        }
    }
    __syncthreads();
    for (int q = threadIdx.x; q < 512; q += 256) {
        const int pl = q >> 3, sc = q & 7;
        *(uint4*)&off_bf[((size_t)(b * HWc) + blockIdx.x*64 + pl)*64 + sc*8] =
            *(const uint4*)&sm[pl][sc*8];
    }
}

// ---- Kernel B: conv3x3 -> per-pixel com records [p][112], m-split waves -----
#define SWZ(px, sc) ((sc) ^ ((px) & 7))

__global__ __launch_bounds__(256) void k_com6(
    const short* __restrict__ off_bf, const short* __restrict__ wfrag,
    const float* __restrict__ b_com, short* __restrict__ com_rec)
{
    __shared__ short smem[14336];       // stage 6x34x64 = 13056 sh; out 128x112 = 14336 sh
    const int seg = blockIdx.x;          // 0..4
    const int yb  = blockIdx.y * 4;      // output rows yb..yb+3
    const int b   = blockIdx.z;
    const int x0  = seg * 32;
    const int tid = threadIdx.x;

    // stage 6 halo rows x 34 px x 64 ch
    for (int c = tid; c < 1632; c += 256) {
        const int r   = c / 272;
        const int rem = c - r * 272;
        const int px  = rem >> 3;
        const int sc  = rem & 7;
        const int gy  = yb + r - 1;
        const int gx  = x0 + px - 1;
        uint4 vv = make_uint4(0u, 0u, 0u, 0u);
        if ((unsigned)gy < (unsigned)Hc && (unsigned)gx < (unsigned)Wc)
            vv = *(const uint4*)&off_bf[(((size_t)b * HWc + gy * Wc + gx) << 6) + (sc << 3)];
        *(uint4*)&smem[((r*34 + px)*8 + SWZ(px, sc)) * 8] = vv;
    }
    __syncthreads();

    const int w    = tid >> 6;           // m-slice wave: m = {0,1},{2,3},{4,5},{6}
    const int lane = tid & 63;
    const int n15  = lane & 15;
    const int g    = lane >> 4;
    const int m0   = w * 2;
    const int nm   = (w == 3) ? 1 : 2;

    f32x4 acc[2][8];
    #pragma unroll
    for (int mm = 0; mm < 2; ++mm)
        #pragma unroll
        for (int t = 0; t < 8; ++t) acc[mm][t] = (f32x4){0.f, 0.f, 0.f, 0.f};

    #pragma unroll
    for (int kk = 0; kk < 9; ++kk) {
        #pragma unroll
        for (int h = 0; h < 2; ++h) {
            const int s = kk*2 + h;
            const int slot = h*4 + g;
            short8 bf[8];
            #pragma unroll
            for (int t = 0; t < 8; ++t) {
                const int r  = t >> 1, xt = t & 1;
                const int ry = r + kk/3;
                const int rx = xt*16 + n15 + (kk % 3);
                bf[t] = *(const short8*)&smem[((ry*34 + rx)*8 + SWZ(rx, slot)) * 8];
            }
            #pragma unroll
            for (int mm = 0; mm < 2; ++mm) {
                if (mm < nm) {
                    const short8 afrag =
                        *(const short8*)&wfrag[(((m0+mm)*18 + s)*64 + lane)*8];
                    #pragma unroll
                    for (int t = 0; t < 8; ++t)
                        acc[mm][t] = __builtin_amdgcn_mfma_f32_16x16x32_bf16(
                            afrag, bf[t], acc[mm][t], 0, 0, 0);
                }
            }
        }
    }
    __syncthreads();   // tile reads done; smem reused as output stage

    #pragma unroll
    for (int mm = 0; mm < 2; ++mm) {
        if (mm < nm) {
            #pragma unroll
            for (int r4 = 0; r4 < 4; ++r4) {
                const int oc = (m0+mm)*16 + g*4 + r4;
                if (oc < COMC) {
                    int pos;
                    if (oc < 72) pos = oc;
                    else { const int q = oc - 72; pos = 72 + (q/9)*10 + (q - (q/9)*9); }
                    const float bo = b_com[oc];
                    #pragma unroll
                    for (int t = 0; t < 8; ++t) {
                        const int r = t >> 1, xt = t & 1;
                        smem[(r*32 + xt*16 + n15)*112 + pos] = f2bf(acc[mm][t][r4] + bo);
                    }
                }
            }
        }
    }
    __syncthreads();

    for (int c = tid; c < 1792; c += 256) {   // 128 records x 14 uint4
        const int pr = c / 14, ch = c - pr * 14;
        const int r = pr >> 5, pxl = pr & 31;
        const int p = (yb + r) * Wc + x0 + pxl;
        *(uint4*)&com_rec[((size_t)b * HWc + p)*112 + ch*8] = *(const uint4*)&smem[pr*112 + ch*8];
    }
}

// ---- Kernel C: DCN gather from GLOBAL fea_gp (no stage_s; 8 blocks/CU) ------
__global__ __launch_bounds__(256, 8) void k_dcn15(
    const float* __restrict__ fea, const short* __restrict__ com_rec,
    const short* __restrict__ fea_gp, const short* __restrict__ wdT,
    const float* __restrict__ b_dcn, float* __restrict__ out)
{
    __shared__ short val_s[9216];      // 72 x 16 x 8 sh = 18432 B (only LDS)
    const int nx = gridDim.x;          // 1600, %8 == 0
    int bid = blockIdx.x;
    bid = (bid & 7) * (nx >> 3) + (bid >> 3);
    const int b = blockIdx.y;
    const int base = bid * 16;
    const int ty = base / Wc;
    const int tx = base - ty * Wc;
    const int tid = threadIdx.x;
    const int w = tid >> 6, lane = tid & 63;
    const int n = lane & 15, g2 = lane >> 4;

    // ---- early issue: residual + bias in MFMA C layout ----
    const size_t outb = ((size_t)b * Cc + (w*16 + g2*4)) * HWc + base + n;
    float resv[4], biasv[4];
    #pragma unroll
    for (int r = 0; r < 4; ++r) {
        resv[r]  = fea[outb + (size_t)r * HWc];
        biasv[r] = b_dcn[w*16 + g2*4 + r];
    }

    // ---- full-wave sample dealing: waves get 3,3,2,1 full-lane iterations ----
    const int ns = (w < 2) ? 3 : (w == 2 ? 2 : 1);
    const int sbase = (w <= 2) ? w * 192 : 512;
    int sk[3];
    const int sg = (lane >> 4) & 3;    // group: per 16-lane
    const int sl = lane & 15;          // local pixel
    unsigned sdydx[3]; float smk[3];
    #pragma unroll
    for (int i = 0; i < 3; ++i) {
        sk[i] = (sbase + i*64 + lane) >> 6;
        if (i < ns) {
            const short* crp = &com_rec[((size_t)b * HWc + base + sl) * 112];
            sdydx[i] = *(const unsigned*)&crp[sg*18 + 2*sk[i]];
            smk[i]   = bf2f(crp[72 + sg*10 + sk[i]]);
        }
    }

    // per-thread group-plane base of fea_gp
    const short* fbf = fea_gp + (((size_t)b*4 + sg) * HWc) * 16;

    // ---- hoisted per-sample pipeline: sigmoid, positions, coeffs, global offs
    float hc00[3], hc01[3], hc10[3], hc11[3];
    int ha00[3], ha01[3], ha10[3], ha11[3];   // element offsets into fbf
    #pragma unroll
    for (int i = 0; i < 3; ++i) {
        if (i < ns) {
            const int k = sk[i];
            const float dy = bflo(sdydx[i]), dx = bfhi(sdydx[i]);
            const float mk = 1.f / (1.f + __expf(-smk[i]));
            const float py  = dy + (float)(k/3 - 1 + ty);
            const float pxf = dx + (float)(k%3 - 1 + tx + sl);
            const float y0f = floorf(py), x0f = floorf(pxf);
            const float wy = py - y0f, wx = pxf - x0f;
            const int y0 = (int)y0f, x0i = (int)x0f;
            const int y1 = y0 + 1,  x1 = x0i + 1;
            const bool vy0 = (y0 >= 0) & (y0 < Hc);
            const bool vy1 = (y1 >= 0) & (y1 < Hc);
            const bool vx0 = (x0i >= 0) & (x0i < Wc);
            const bool vx1 = (x1 >= 0) & (x1 < Wc);
            hc00[i] = (vy0 && vx0) ? (1.f-wy)*(1.f-wx)*mk : 0.f;
            hc01[i] = (vy0 && vx1) ? (1.f-wy)*wx*mk       : 0.f;
            hc10[i] = (vy1 && vx0) ? wy*(1.f-wx)*mk       : 0.f;
            hc11[i] = (vy1 && vx1) ? wy*wx*mk             : 0.f;
            const int y0c = min(max(y0, 0), Hc-1), y1c = min(max(y1, 0), Hc-1);
            const int x0c = min(max(x0i, 0), Wc-1), x1c = min(max(x1, 0), Wc-1);
            ha00[i] = (y0c*Wc + x0c) << 4;
            ha01[i] = (y0c*Wc + x1c) << 4;
            ha10[i] = (y1c*Wc + x0c) << 4;
            ha11[i] = (y1c*Wc + x1c) << 4;
        }
    }

    // ---- phase 1: gather straight from global (L2-resident via XCD swizzle) --
    #pragma unroll
    for (int i = 0; i < 3; ++i) {
        if (i < ns) {
            const float c00 = hc00[i], c01 = hc01[i], c10 = hc10[i], c11 = hc11[i];
            const short* r00 = fbf + ha00[i];
            const short* r01 = fbf + ha01[i];
            const short* r10 = fbf + ha10[i];
            const short* r11 = fbf + ha11[i];
            const uint4 a00 = *(const uint4*)r00, b00 = *(const uint4*)(r00 + 8);
            const uint4 a01 = *(const uint4*)r01, b01 = *(const uint4*)(r01 + 8);
            const uint4 a10 = *(const uint4*)r10, b10 = *(const uint4*)(r10 + 8);
            const uint4 a11 = *(const uint4*)r11, b11 = *(const uint4*)(r11 + 8);
            unsigned uo[8];
            {
                const unsigned* p00 = (const unsigned*)&a00;
                const unsigned* p01 = (const unsigned*)&a01;
                const unsigned* p10 = (const unsigned*)&a10;
                const unsigned* p11 = (const unsigned*)&a11;
                #pragma unroll
                for (int wi = 0; wi < 4; ++wi) {
                    const f32x2 v = bf2x2(p00[wi])*c00 + bf2x2(p01[wi])*c01
                                  + bf2x2(p10[wi])*c10 + bf2x2(p11[wi])*c11;
                    uo[wi] = packbf_perm(v.x, v.y);
                }
            }
            {
                const unsigned* p00 = (const unsigned*)&b00;
                const unsigned* p01 = (const unsigned*)&b01;
                const unsigned* p10 = (const unsigned*)&b10;
                const unsigned* p11 = (const unsigned*)&b11;
                #pragma unroll
                for (int wi = 0; wi < 4; ++wi) {
                    const f32x2 v = bf2x2(p00[wi])*c00 + bf2x2(p01[wi])*c01
                                  + bf2x2(p10[wi])*c10 + bf2x2(p11[wi])*c11;
                    uo[4 + wi] = packbf_perm(v.x, v.y);
                }
            }
            const int cc = sk[i]*8 + sg*2;   // chunk row; 16-lane group writes 256B run
            *(uint4*)&val_s[((cc    )*16 + sl) * 8] = make_uint4(uo[0], uo[1], uo[2], uo[3]);
            *(uint4*)&val_s[((cc + 1)*16 + sl) * 8] = make_uint4(uo[4], uo[5], uo[6], uo[7]);
        }
    }

    // ---- prefetch afrags before the barrier: L2 latency drains in the wait ---
    const short* wp = wdT + ((w*18)*64 + lane)*8;
    short8 af[18];
    #pragma unroll
    for (int s = 0; s < 18; ++s) af[s] = *(const short8*)&wp[(s*64) * 8];
    __syncthreads();

    // ---- phase 2: wave = o-tile; 18 MFMA/wave; pure LDS + MFMA ----
    f32x4 acc = (f32x4){0.f, 0.f, 0.f, 0.f};
    __builtin_amdgcn_s_setprio(1);
    #pragma unroll
    for (int s = 0; s < 18; ++s) {
        const short8 bfrag = *(const short8*)&val_s[((s*4 + g2)*16 + n) * 8];
        acc = __builtin_amdgcn_mfma_f32_16x16x32_bf16(af[s], bfrag, acc, 0, 0, 0);
    }
    __builtin_amdgcn_s_setprio(0);
    #pragma unroll
    for (int r = 0; r < 4; ++r)
        out[outb + (size_t)r * HWc] = resv[r] + fmaxf(acc[r] + biasv[r], 0.f);
}

extern "C" void kernel_launch(void* const* d_in, const int* in_sizes, int n_in,
                              void* d_out, int out_size, void* d_ws, size_t ws_size,
                              hipStream_t stream) {
    const float* fea   = (const float*)d_in[0];
    const float* w_off = (const float*)d_in[1];
    const float* bn_g  = (const float*)d_in[2];
    const float* bn_b  = (const float*)d_in[3];
    const float* bn_m  = (const float*)d_in[4];
    const float* bn_v  = (const float*)d_in[5];
    const float* w_com = (const float*)d_in[6];
    const float* b_com = (const float*)d_in[7];
    const float* w_dcn = (const float*)d_in[8];
    const float* b_dcn = (const float*)d_in[9];
    float* out = (float*)d_out;

    char* ws = (char*)d_ws;
    short* com_rec  = (short*)ws;                          // 22,937,600 B
    short* off_bf   = (short*)(ws + 22937600);             // 13,107,200 B
    short* fea_gp   = (short*)(ws + 36044800);             // 13,107,200 B
    short* wfrag    = (short*)(ws + 49152000);             //    129,024 B
    short* wdT      = (short*)(ws + 49281024);             //     73,728 B
    short* wof_frag = (short*)(ws + 49354752);             //      8,192 B
    float* shift    = (float*)(ws + 49362944);             //        256 B

    k_prep2<<<252, 256, 0, stream>>>(w_off, bn_g, bn_b, bn_m, bn_v,
                                     w_com, w_dcn, wof_frag, shift, wfrag, wdT);

    dim3 gA(HWc / 64, 4);
    k_off3<<<gA, 256, 0, stream>>>(fea, wof_frag, shift, off_bf, fea_gp);

    dim3 gB(5, Hc / 4, 4);
    k_com6<<<gB, 256, 0, stream>>>(off_bf, wfrag, b_com, com_rec);

    dim3 gC(HWc / 16, 4);
    k_dcn15<<<gC, 256, 0, stream>>>(fea, com_rec, fea_gp, wdT, b_dcn, out);
}

// Round 21
// 93.353 us; speedup vs baseline: 1.7284x; 1.7284x over previous
//
#include <hip/hip_runtime.h>
#include <math.h>

#define Hc 160
#define Wc 160
#define HWc (Hc*Wc)
#define Cc 64
#define COMC 108

typedef __attribute__((ext_vector_type(8))) short short8;
typedef __attribute__((ext_vector_type(4))) float f32x4;
typedef __attribute__((ext_vector_type(2))) float f32x2;

__device__ inline short f2bf(float f) {
    union { float f; unsigned u; } v; v.f = f;
    unsigned r = (v.u + 0x7FFFu + ((v.u >> 16) & 1u)) >> 16;
    return (short)r;
}
__device__ inline float bf2f(short s) {
    union { unsigned u; float f; } v; v.u = ((unsigned)(unsigned short)s) << 16; return v.f;
}
__device__ inline float bflo(unsigned u) {
    union { unsigned u; float f; } v; v.u = u << 16; return v.f;
}
__device__ inline float bfhi(unsigned u) {
    union { unsigned u; float f; } v; v.u = u & 0xFFFF0000u; return v.f;
}
__device__ inline f32x2 bf2x2(unsigned u) {
    union { unsigned u; float f; } lo, hi;
    lo.u = u << 16; hi.u = u & 0xFFFF0000u;
    return (f32x2){lo.f, hi.f};
}
// round-half-up pack of 2 floats -> 1 dword of 2 bf16, via v_perm (3 ops)
__device__ inline unsigned packbf_perm(float lo, float hi) {
    union { float f; unsigned u; } a, c; a.f = lo; c.f = hi;
    return __builtin_amdgcn_perm(c.u + 0x8000u, a.u + 0x8000u, 0x07060302u);
}

// ---- prep: fragment-ordered bf16 weights for all three MFMA stages ----------
__global__ __launch_bounds__(256) void k_prep2(
    const float* __restrict__ w_off,
    const float* __restrict__ bn_g, const float* __restrict__ bn_b,
    const float* __restrict__ bn_m, const float* __restrict__ bn_v,
    const float* __restrict__ w_com, const float* __restrict__ w_dcn,
    short* __restrict__ wof_frag, float* __restrict__ shift,
    short* __restrict__ wfrag, short* __restrict__ wdT)
{
    const int t = blockIdx.x * 256 + threadIdx.x;
    if (t < 64) {
        const float scale = bn_g[t] * __frsqrt_rn(bn_v[t] + 1e-5f);
        shift[t] = bn_b[t] - bn_m[t] * scale;
    }
    if (t < 4096) {  // wof_frag [4m][2s][64 lane][8 j]
        const int j = t & 7;
        const int lane = (t >> 3) & 63;
        const int v = t >> 9;            // m*2+s
        const int s = v & 1, m = v >> 1;
        const int o = m*16 + (lane & 15);
        const int i = s*32 + (lane >> 4)*8 + j;
        const float scale = bn_g[o] * __frsqrt_rn(bn_v[o] + 1e-5f);
        wof_frag[t] = f2bf(w_off[o*64 + i] * scale);
    }
    if (t < 64512) {  // wfrag [7 mtile][18 s][64 lane][8 j]; K-order = kk*64 + i
        const int j = t & 7;
        const int lane = (t >> 3) & 63;
        const int v = t >> 9;            // 0..125
        const int s = v % 18, m = v / 18;
        const int kk = s >> 1, h = s & 1;
        const int o = m*16 + (lane & 15);
        const int i = h*32 + (lane >> 4)*8 + j;
        wfrag[t] = (o < COMC) ? f2bf(w_com[(o*64 + i)*9 + kk]) : (short)0;
    }
    if (t < 36864) {  // wdT [4 mtile][18 s][64 lane][8 j]; K-order = kk*64 + ch
        const int j = t & 7;
        const int lane = (t >> 3) & 63;
        const int v = t >> 9;            // 0..71
        const int s = v % 18, m = v / 18;
        const int o = m*16 + (lane & 15);
        const int q = s*32 + (lane >> 4)*8 + j;  // 0..575
        const int ch = q & 63, kk = q >> 6;
        wdT[t] = f2bf(w_dcn[o*576 + ch*9 + kk]);
    }
}

// ---- Kernel A: off_bf = BN(fea @ w_off^T) via MFMA; emits group-planar fea_gp
__global__ __launch_bounds__(256) void k_off3(
    const float* __restrict__ fea, const short* __restrict__ wof_frag,
    const float* __restrict__ shift,
    short* __restrict__ off_bf, short* __restrict__ fea_gp)
{
    __shared__ short sm[64][72];
    const int b = blockIdx.y;
    const int w = threadIdx.x >> 6, lane = threadIdx.x & 63;
    const int n = lane & 15, g = lane >> 4;
    const int p = blockIdx.x * 64 + w * 16 + n;
    const float* f = fea + (size_t)b * Cc * HWc + p;

    short8 bfrag[2];
    #pragma unroll
    for (int s = 0; s < 2; ++s) {
        #pragma unroll
        for (int j = 0; j < 8; ++j)
            bfrag[s][j] = f2bf(f[(size_t)(s*32 + g*8 + j) * HWc]);
        const int gg = s*2 + (g >> 1);
        *(short8*)&fea_gp[(((size_t)b*4 + gg)*HWc + p)*16 + (g & 1)*8] = bfrag[s];
    }

    f32x4 acc[4];
    #pragma unroll
    for (int m = 0; m < 4; ++m) acc[m] = (f32x4){0.f, 0.f, 0.f, 0.f};
    #pragma unroll
    for (int s = 0; s < 2; ++s) {
        #pragma unroll
        for (int m = 0; m < 4; ++m) {
            const short8 afrag = *(const short8*)&wof_frag[((m*2 + s)*64 + lane)*8];
            acc[m] = __builtin_amdgcn_mfma_f32_16x16x32_bf16(afrag, bfrag[s], acc[m], 0, 0, 0);
        }
    }
    #pragma unroll
    for (int m = 0; m < 4; ++m) {
        #pragma unroll
        for (int r = 0; r < 4; ++r) {
            const int o = m*16 + g*4 + r;
            sm[w*16 + n][o] = f2bf(acc[m][r] + shift[o]);
        }
    }
    __syncthreads();
    for (int q = threadIdx.x; q < 512; q += 256) {
        const int pl = q >> 3, sc = q & 7;
        *(uint4*)&off_bf[((size_t)(b * HWc) + blockIdx.x*64 + pl)*64 + sc*8] =
            *(const uint4*)&sm[pl][sc*8];
    }
}

// ---- Kernel B: conv3x3 -> per-pixel com records [p][112], m-split waves -----
#define SWZ(px, sc) ((sc) ^ ((px) & 7))

__global__ __launch_bounds__(256) void k_com6(
    const short* __restrict__ off_bf, const short* __restrict__ wfrag,
    const float* __restrict__ b_com, short* __restrict__ com_rec)
{
    __shared__ short smem[14336];       // stage 6x34x64 = 13056 sh; out 128x112 = 14336 sh
    const int seg = blockIdx.x;          // 0..4
    const int yb  = blockIdx.y * 4;      // output rows yb..yb+3
    const int b   = blockIdx.z;
    const int x0  = seg * 32;
    const int tid = threadIdx.x;

    // stage 6 halo rows x 34 px x 64 ch
    for (int c = tid; c < 1632; c += 256) {
        const int r   = c / 272;
        const int rem = c - r * 272;
        const int px  = rem >> 3;
        const int sc  = rem & 7;
        const int gy  = yb + r - 1;
        const int gx  = x0 + px - 1;
        uint4 vv = make_uint4(0u, 0u, 0u, 0u);
        if ((unsigned)gy < (unsigned)Hc && (unsigned)gx < (unsigned)Wc)
            vv = *(const uint4*)&off_bf[(((size_t)b * HWc + gy * Wc + gx) << 6) + (sc << 3)];
        *(uint4*)&smem[((r*34 + px)*8 + SWZ(px, sc)) * 8] = vv;
    }
    __syncthreads();

    const int w    = tid >> 6;           // m-slice wave: m = {0,1},{2,3},{4,5},{6}
    const int lane = tid & 63;
    const int n15  = lane & 15;
    const int g    = lane >> 4;
    const int m0   = w * 2;
    const int nm   = (w == 3) ? 1 : 2;

    f32x4 acc[2][8];
    #pragma unroll
    for (int mm = 0; mm < 2; ++mm)
        #pragma unroll
        for (int t = 0; t < 8; ++t) acc[mm][t] = (f32x4){0.f, 0.f, 0.f, 0.f};

    #pragma unroll
    for (int kk = 0; kk < 9; ++kk) {
        #pragma unroll
        for (int h = 0; h < 2; ++h) {
            const int s = kk*2 + h;
            const int slot = h*4 + g;
            short8 bf[8];
            #pragma unroll
            for (int t = 0; t < 8; ++t) {
                const int r  = t >> 1, xt = t & 1;
                const int ry = r + kk/3;
                const int rx = xt*16 + n15 + (kk % 3);
                bf[t] = *(const short8*)&smem[((ry*34 + rx)*8 + SWZ(rx, slot)) * 8];
            }
            #pragma unroll
            for (int mm = 0; mm < 2; ++mm) {
                if (mm < nm) {
                    const short8 afrag =
                        *(const short8*)&wfrag[(((m0+mm)*18 + s)*64 + lane)*8];
                    #pragma unroll
                    for (int t = 0; t < 8; ++t)
                        acc[mm][t] = __builtin_amdgcn_mfma_f32_16x16x32_bf16(
                            afrag, bf[t], acc[mm][t], 0, 0, 0);
                }
            }
        }
    }
    __syncthreads();   // tile reads done; smem reused as output stage

    #pragma unroll
    for (int mm = 0; mm < 2; ++mm) {
        if (mm < nm) {
            #pragma unroll
            for (int r4 = 0; r4 < 4; ++r4) {
                const int oc = (m0+mm)*16 + g*4 + r4;
                if (oc < COMC) {
                    int pos;
                    if (oc < 72) pos = oc;
                    else { const int q = oc - 72; pos = 72 + (q/9)*10 + (q - (q/9)*9); }
                    const float bo = b_com[oc];
                    #pragma unroll
                    for (int t = 0; t < 8; ++t) {
                        const int r = t >> 1, xt = t & 1;
                        smem[(r*32 + xt*16 + n15)*112 + pos] = f2bf(acc[mm][t][r4] + bo);
                    }
                }
            }
        }
    }
    __syncthreads();

    for (int c = tid; c < 1792; c += 256) {   // 128 records x 14 uint4
        const int pr = c / 14, ch = c - pr * 14;
        const int r = pr >> 5, pxl = pr & 31;
        const int p = (yb + r) * Wc + x0 + pxl;
        *(uint4*)&com_rec[((size_t)b * HWc + p)*112 + ch*8] = *(const uint4*)&smem[pr*112 + ch*8];
    }
}

// ---- Kernel C: DCN gather; transposed val layout; 18-deep afrag prefetch ----
#define SROW 360
#define SG   (7*SROW)

__global__ __launch_bounds__(256, 4) void k_dcn12(
    const float* __restrict__ fea, const short* __restrict__ com_rec,
    const short* __restrict__ fea_gp, const short* __restrict__ wdT,
    const float* __restrict__ b_dcn, float* __restrict__ out)
{
    __shared__ short stage_s[4*SG];    // 10080 sh = 20160 B
    __shared__ short val_s[9216];      // 72 x 16 x 8 sh = 18432 B
    const int nx = gridDim.x;          // 1600, %8 == 0
    int bid = blockIdx.x;
    bid = (bid & 7) * (nx >> 3) + (bid >> 3);
    const int b = blockIdx.y;
    const int base = bid * 16;
    const int ty = base / Wc;
    const int tx = base - ty * Wc;
    const int tid = threadIdx.x;
    const int w = tid >> 6, lane = tid & 63;
    const int n = lane & 15, g2 = lane >> 4;

    // ---- early issue: residual + bias in MFMA C layout ----
    const size_t outb = ((size_t)b * Cc + (w*16 + g2*4)) * HWc + base + n;
    float resv[4], biasv[4];
    #pragma unroll
    for (int r = 0; r < 4; ++r) {
        resv[r]  = fea[outb + (size_t)r * HWc];
        biasv[r] = b_dcn[w*16 + g2*4 + r];
    }

    // ---- full-wave sample dealing: waves get 3,3,2,1 full-lane iterations ----
    const int ns = (w < 2) ? 3 : (w == 2 ? 2 : 1);
    const int sbase = (w <= 2) ? w * 192 : 512;
    int sk[3];
    const int sg = (lane >> 4) & 3;    // group: per 16-lane
    const int sl = lane & 15;          // local pixel
    unsigned sdydx[3]; float smk[3];
    #pragma unroll
    for (int i = 0; i < 3; ++i) {
        sk[i] = (sbase + i*64 + lane) >> 6;
        if (i < ns) {
            const short* crp = &com_rec[((size_t)b * HWc + base + sl) * 112];
            sdydx[i] = *(const unsigned*)&crp[sg*18 + 2*sk[i]];
            smk[i]   = bf2f(crp[72 + sg*10 + sk[i]]);
        }
    }

    // ---- stage fea_gp window (divide-free): wave = group, lane = (col,half) --
    if (lane < 44) {
        const int c = lane >> 1, h = lane & 1;
        const int gx = min(max(tx - 3 + c, 0), Wc-1);
        const short* src = fea_gp + (((size_t)b*4 + w)*HWc)*16;
        #pragma unroll
        for (int r = 0; r < 7; ++r) {
            const int gy = min(max(ty - 3 + r, 0), Hc-1);
            *(uint4*)&stage_s[w*SG + r*SROW + c*16 + h*8] =
                *(const uint4*)&src[(gy*Wc + gx)*16 + h*8];
        }
    }
    __syncthreads();

    // ---- phase 1: bilinear gather from LDS (pk-f32 math) ----
    #pragma unroll
    for (int i = 0; i < 3; ++i) {
        if (i < ns) {
            const int k = sk[i];
            const float dy = bflo(sdydx[i]), dx = bfhi(sdydx[i]);
            const float mk = 1.f / (1.f + __expf(-smk[i]));
            const float py  = dy + (float)(k/3 - 1 + ty);
            const float pxf = dx + (float)(k%3 - 1 + tx + sl);
            const float y0f = floorf(py), x0f = floorf(pxf);
            const float wy = py - y0f, wx = pxf - x0f;
            const int y0 = (int)y0f, x0i = (int)x0f;
            const int y1 = y0 + 1,  x1 = x0i + 1;
            const bool vy0 = (y0 >= 0) & (y0 < Hc);
            const bool vy1 = (y1 >= 0) & (y1 < Hc);
            const bool vx0 = (x0i >= 0) & (x0i < Wc);
            const bool vx1 = (x1 >= 0) & (x1 < Wc);
            const float c00 = (vy0 && vx0) ? (1.f-wy)*(1.f-wx)*mk : 0.f;
            const float c01 = (vy0 && vx1) ? (1.f-wy)*wx*mk       : 0.f;
            const float c10 = (vy1 && vx0) ? wy*(1.f-wx)*mk       : 0.f;
            const float c11 = (vy1 && vx1) ? wy*wx*mk             : 0.f;
            const int y0c = min(max(y0, 0), Hc-1), y1c = min(max(y1, 0), Hc-1);
            const int x0c = min(max(x0i, 0), Wc-1), x1c = min(max(x1, 0), Wc-1);
            const int wr0 = min(max(y0c - (ty-3), 0), 6);
            const int wr1 = min(max(y1c - (ty-3), 0), 6);
            const int wc0 = min(max(x0c - (tx-3), 0), 21);
            const int wc1 = min(max(x1c - (tx-3), 0), 21);
            const short* sgp = &stage_s[sg*SG];
            const short* r00 = sgp + wr0*SROW + wc0*16;
            const short* r01 = sgp + wr0*SROW + wc1*16;
            const short* r10 = sgp + wr1*SROW + wc0*16;
            const short* r11 = sgp + wr1*SROW + wc1*16;
            const uint4 a00 = *(const uint4*)r00, b00 = *(const uint4*)(r00 + 8);
            const uint4 a01 = *(const uint4*)r01, b01 = *(const uint4*)(r01 + 8);
            const uint4 a10 = *(const uint4*)r10, b10 = *(const uint4*)(r10 + 8);
            const uint4 a11 = *(const uint4*)r11, b11 = *(const uint4*)(r11 + 8);
            unsigned uo[8];
            {
                const unsigned* p00 = (const unsigned*)&a00;
                const unsigned* p01 = (const unsigned*)&a01;
                const unsigned* p10 = (const unsigned*)&a10;
                const unsigned* p11 = (const unsigned*)&a11;
                #pragma unroll
                for (int wi = 0; wi < 4; ++wi) {
                    const f32x2 v = bf2x2(p00[wi])*c00 + bf2x2(p01[wi])*c01
                                  + bf2x2(p10[wi])*c10 + bf2x2(p11[wi])*c11;
                    uo[wi] = packbf_perm(v.x, v.y);
                }
            }
            {
                const unsigned* p00 = (const unsigned*)&b00;
                const unsigned* p01 = (const unsigned*)&b01;
                const unsigned* p10 = (const unsigned*)&b10;
                const unsigned* p11 = (const unsigned*)&b11;
                #pragma unroll
                for (int wi = 0; wi < 4; ++wi) {
                    const f32x2 v = bf2x2(p00[wi])*c00 + bf2x2(p01[wi])*c01
                                  + bf2x2(p10[wi])*c10 + bf2x2(p11[wi])*c11;
                    uo[4 + wi] = packbf_perm(v.x, v.y);
                }
            }
            const int cc = k*8 + sg*2;   // chunk row; 16-lane group writes 256B run
            *(uint4*)&val_s[((cc    )*16 + sl) * 8] = make_uint4(uo[0], uo[1], uo[2], uo[3]);
            *(uint4*)&val_s[((cc + 1)*16 + sl) * 8] = make_uint4(uo[4], uo[5], uo[6], uo[7]);
        }
    }

    // ---- prefetch ALL 18 afrags (72 VGPR) before the barrier: their L2
    //      latency drains during the barrier wait instead of inside phase 2
    const short* wp = wdT + ((w*18)*64 + lane)*8;
    short8 af[18];
    #pragma unroll
    for (int s = 0; s < 18; ++s) af[s] = *(const short8*)&wp[(s*64) * 8];
    __syncthreads();

    // ---- phase 2: wave = o-tile; 18 MFMA/wave; pure LDS + MFMA ----
    f32x4 acc = (f32x4){0.f, 0.f, 0.f, 0.f};
    __builtin_amdgcn_s_setprio(1);
    #pragma unroll
    for (int s = 0; s < 18; ++s) {
        const short8 bfrag = *(const short8*)&val_s[((s*4 + g2)*16 + n) * 8];
        acc = __builtin_amdgcn_mfma_f32_16x16x32_bf16(af[s], bfrag, acc, 0, 0, 0);
    }
    __builtin_amdgcn_s_setprio(0);
    #pragma unroll
    for (int r = 0; r < 4; ++r)
        out[outb + (size_t)r * HWc] = resv[r] + fmaxf(acc[r] + biasv[r], 0.f);
}

extern "C" void kernel_launch(void* const* d_in, const int* in_sizes, int n_in,
                              void* d_out, int out_size, void* d_ws, size_t ws_size,
                              hipStream_t stream) {
    const float* fea   = (const float*)d_in[0];
    const float* w_off = (const float*)d_in[1];
    const float* bn_g  = (const float*)d_in[2];
    const float* bn_b  = (const float*)d_in[3];
    const float* bn_m  = (const float*)d_in[4];
    const float* bn_v  = (const float*)d_in[5];
    const float* w_com = (const float*)d_in[6];
    const float* b_com = (const float*)d_in[7];
    const float* w_dcn = (const float*)d_in[8];
    const float* b_dcn = (const float*)d_in[9];
    float* out = (float*)d_out;

    char* ws = (char*)d_ws;
    short* com_rec  = (short*)ws;                          // 22,937,600 B
    short* off_bf   = (short*)(ws + 22937600);             // 13,107,200 B
    short* fea_gp   = (short*)(ws + 36044800);             // 13,107,200 B
    short* wfrag    = (short*)(ws + 49152000);             //    129,024 B
    short* wdT      = (short*)(ws + 49281024);             //     73,728 B
    short* wof_frag = (short*)(ws + 49354752);             //      8,192 B
    float* shift    = (float*)(ws + 49362944);             //        256 B

    k_prep2<<<252, 256, 0, stream>>>(w_off, bn_g, bn_b, bn_m, bn_v,
                                     w_com, w_dcn, wof_frag, shift, wfrag, wdT);

    dim3 gA(HWc / 64, 4);
    k_off3<<<gA, 256, 0, stream>>>(fea, wof_frag, shift, off_bf, fea_gp);

    dim3 gB(5, Hc / 4, 4);
    k_com6<<<gB, 256, 0, stream>>>(off_bf, wfrag, b_com, com_rec);

    dim3 gC(HWc / 16, 4);
    k_dcn12<<<gC, 256, 0, stream>>>(fea, com_rec, fea_gp, wdT, b_dcn, out);
}